// Round 5
// baseline (354.797 us; speedup 1.0000x reference)
//
#include <hip/hip_runtime.h>

#define N_NODES 50000
#define N_EDGES 400000
#define F_INP 5
#define HD 256          // HEADS*DIM = 2*128
#define BN_EPS 1e-5f

// ---- workspace layout (float offsets) ----
#define OFF_HBN   0          // N*8  = 400000 (padded rows: 5 used + 3 pad)
#define OFF_ACC   400000     // N*16 = 800000 (den0,S0[5],den1,S1[5],cnt,pad3)
#define OFF_WPK   1200000    // 256*16 = 4096 packed channel weights

// prep: zero acc + BN1 -> hbn8 + pack per-channel weights [256][16]
// wpk[c] = { Wl[0..4][c], Wr[0..4][c], bl[c]+br[c], We[c], 0.6*att[c], 0.4*att[c], 0, 0 }
__global__ void k_prep(const float* __restrict__ h, const float* __restrict__ g1,
                       const float* __restrict__ be1, const float* __restrict__ rm1,
                       const float* __restrict__ rv1,
                       const float* __restrict__ Wl, const float* __restrict__ bl,
                       const float* __restrict__ Wr, const float* __restrict__ br,
                       const float* __restrict__ We, const float* __restrict__ att,
                       float* __restrict__ hbn8, float* __restrict__ acc,
                       float* __restrict__ wpk) {
    int i = blockIdx.x * blockDim.x + threadIdx.x;
    if (i < N_NODES * 16) acc[i] = 0.f;
    if (i < N_NODES * 8) {
        int f = i & 7, n = i >> 3;
        float v = 0.f;
        if (f < F_INP) {
            float x = h[n * F_INP + f];
            v = (x - rm1[f]) * rsqrtf(rv1[f] + BN_EPS) * g1[f] + be1[f];
        }
        hbn8[i] = v;
    }
    if (i < HD) {
        float a = att[i];
#pragma unroll
        for (int f = 0; f < F_INP; ++f) {
            wpk[i * 16 + f]     = Wl[f * HD + i];
            wpk[i * 16 + 5 + f] = Wr[f * HD + i];
        }
        wpk[i * 16 + 10] = bl[i] + br[i];
        wpk[i * 16 + 11] = We[i];
        wpk[i * 16 + 12] = 0.6f * a;
        wpk[i * 16 + 13] = 0.4f * a;
        wpk[i * 16 + 14] = 0.f;
        wpk[i * 16 + 15] = 0.f;
    }
}

// One THREAD per edge; channels are the wave-uniform streaming dimension, so
// all weight reads are scalar (SGPR) loads and no cross-lane ops are needed.
// att*leaky(u) == (0.6*att)*u + (0.4*att)*|u|  (abs = free VOP3 modifier).
__launch_bounds__(256)
__global__ void k_edge(const float* __restrict__ hbn8, const int* __restrict__ ei,
                       const float* __restrict__ ew, const float* __restrict__ wpk,
                       float* __restrict__ acc) {
    int e = blockIdx.x * blockDim.x + threadIdx.x;
    if (e >= N_EDGES) return;
    int src = ei[e], dst = ei[N_EDGES + e];
    float w = ew[e];
    float4 s4 = *(const float4*)&hbn8[src * 8];
    float hs0 = s4.x, hs1 = s4.y, hs2 = s4.z, hs3 = s4.w;
    float hs4 = hbn8[src * 8 + 4];
    float4 d4 = *(const float4*)&hbn8[dst * 8];
    float hd0 = d4.x, hd1 = d4.y, hd2 = d4.z, hd3 = d4.w;
    float hd4 = hbn8[dst * 8 + 4];

    float acc0 = 0.f, acc1 = 0.f;
#pragma unroll 4
    for (int c = 0; c < 128; ++c) {
        const float* W = &wpk[c * 16];
        float u = W[10] + w * W[11];
        u += hs0 * W[0] + hs1 * W[1] + hs2 * W[2] + hs3 * W[3] + hs4 * W[4];
        u += hd0 * W[5] + hd1 * W[6] + hd2 * W[7] + hd3 * W[8] + hd4 * W[9];
        acc0 += W[12] * u + W[13] * fabsf(u);
    }
#pragma unroll 4
    for (int c = 128; c < 256; ++c) {
        const float* W = &wpk[c * 16];
        float u = W[10] + w * W[11];
        u += hs0 * W[0] + hs1 * W[1] + hs2 * W[2] + hs3 * W[3] + hs4 * W[4];
        u += hd0 * W[5] + hd1 * W[6] + hd2 * W[7] + hd3 * W[8] + hd4 * W[9];
        acc1 += W[12] * u + W[13] * fabsf(u);
    }
    float ex0 = __expf(acc0), ex1 = __expf(acc1);
    float* ap = &acc[dst * 16];
    atomicAdd(ap + 0, ex0);
    atomicAdd(ap + 1, ex0 * hs0);
    atomicAdd(ap + 2, ex0 * hs1);
    atomicAdd(ap + 3, ex0 * hs2);
    atomicAdd(ap + 4, ex0 * hs3);
    atomicAdd(ap + 5, ex0 * hs4);
    atomicAdd(ap + 6, ex1);
    atomicAdd(ap + 7, ex1 * hs0);
    atomicAdd(ap + 8, ex1 * hs1);
    atomicAdd(ap + 9, ex1 * hs2);
    atomicAdd(ap + 10, ex1 * hs3);
    atomicAdd(ap + 11, ex1 * hs4);
    atomicAdd(ap + 12, 1.0f);
}

// fused: reconstruct aggregated feature from 12 moments -> fc1(LDS W1) -> BN2
//        -> lrelu -> fc2 -> out
__launch_bounds__(256, 1)
__global__ void k_mlp(const float* __restrict__ acc,
                      const float* __restrict__ Wl, const float* __restrict__ bl,
                      const float* __restrict__ bias_gat,
                      const float* __restrict__ W1, const float* __restrict__ b1,
                      const float* __restrict__ g2, const float* __restrict__ be2,
                      const float* __restrict__ rm2, const float* __restrict__ rv2,
                      const float* __restrict__ W2, const float* __restrict__ b2,
                      float* __restrict__ out) {
    __shared__ float wsh[128 * 128];
    __shared__ float xsh[8][128];
    __shared__ float wlsh[5 * 256 + 256 + 128];   // Wl | bl | bias_gat
    __shared__ float accsh[8][16];
    int t = threadIdx.x;
    for (int i = t; i < 128 * 128 / 4; i += 256)
        ((float4*)wsh)[i] = ((const float4*)W1)[i];
    for (int i = t; i < 5 * 256; i += 256) wlsh[i] = Wl[i];
    wlsh[1280 + t] = bl[t];
    if (t < 128) wlsh[1536 + t] = bias_gat[t];
    __syncthreads();
    const float* WL = wlsh;
    const float* BL = wlsh + 1280;
    const float* BG = wlsh + 1536;

    int nl = t >> 5;      // local node 0..7
    int jg = t & 31;      // output group
    int j4 = jg * 4;

    const int ngroups = (N_NODES + 7) / 8;
    for (int g = blockIdx.x; g < ngroups; g += gridDim.x) {
        int n = g * 8 + nl;
        if (t < 128) {
            int node = g * 8 + (t >> 4);
            accsh[t >> 4][t & 15] = (node < N_NODES) ? acc[node * 16 + (t & 15)] : 0.f;
        }
        __syncthreads();
        bool valid = n < N_NODES;
        if (valid) {
            float den0 = accsh[nl][0], den1 = accsh[nl][6], cntv = accsh[nl][12];
            float r0 = 1.f / (den0 + 1e-16f), r1 = 1.f / (den1 + 1e-16f);
            float scale = 0.5f / fmaxf(cntv, 1.f);
            float c0 = den0 * r0 * scale, c1 = den1 * r1 * scale;
            float T0[F_INP], T1[F_INP];
#pragma unroll
            for (int f = 0; f < F_INP; ++f) {
                T0[f] = accsh[nl][1 + f] * r0 * scale;
                T1[f] = accsh[nl][7 + f] * r1 * scale;
            }
#pragma unroll
            for (int q = 0; q < 4; ++q) {
                int d = j4 + q;
                float xv = c0 * BL[d] + c1 * BL[128 + d];
#pragma unroll
                for (int f = 0; f < F_INP; ++f)
                    xv += T0[f] * WL[f * HD + d] + T1[f] * WL[f * HD + 128 + d];
                xsh[nl][d] = xv + BG[d];
            }
            float4 a4 = *(const float4*)&b1[j4];
#pragma unroll 8
            for (int k = 0; k < 128; ++k) {
                float xv = xsh[nl][k];
                float4 w = *(const float4*)&wsh[k * 128 + j4];
                a4.x += xv * w.x; a4.y += xv * w.y;
                a4.z += xv * w.z; a4.w += xv * w.w;
            }
            float4 rm = *(const float4*)&rm2[j4];
            float4 rv = *(const float4*)&rv2[j4];
            float4 gg = *(const float4*)&g2[j4];
            float4 bb = *(const float4*)&be2[j4];
            float a[4];
            a[0] = (a4.x - rm.x) * rsqrtf(rv.x + BN_EPS) * gg.x + bb.x;
            a[1] = (a4.y - rm.y) * rsqrtf(rv.y + BN_EPS) * gg.y + bb.y;
            a[2] = (a4.z - rm.z) * rsqrtf(rv.z + BN_EPS) * gg.z + bb.z;
            a[3] = (a4.w - rm.w) * rsqrtf(rv.w + BN_EPS) * gg.w + bb.w;
#pragma unroll
            for (int q = 0; q < 4; ++q) a[q] = fmaxf(a[q], 0.01f * a[q]);
            float pf[5] = {0.f, 0.f, 0.f, 0.f, 0.f};
#pragma unroll
            for (int q = 0; q < 4; ++q)
#pragma unroll
                for (int f = 0; f < 5; ++f) pf[f] += a[q] * W2[(j4 + q) * 5 + f];
#pragma unroll
            for (int m = 16; m; m >>= 1)
#pragma unroll
                for (int f = 0; f < 5; ++f) pf[f] += __shfl_xor(pf[f], m);
            if (jg == 0) {
#pragma unroll
                for (int f = 0; f < 5; ++f) out[n * 5 + f] = pf[f] + b2[f];
            }
        }
        __syncthreads();
    }
}

extern "C" void kernel_launch(void* const* d_in, const int* in_sizes, int n_in,
                              void* d_out, int out_size, void* d_ws, size_t ws_size,
                              hipStream_t stream) {
    const float* h    = (const float*)d_in[0];
    const int*   ei   = (const int*)d_in[1];
    const float* ew   = (const float*)d_in[2];
    const float* g1   = (const float*)d_in[3];
    const float* be1  = (const float*)d_in[4];
    const float* rm1  = (const float*)d_in[5];
    const float* rv1  = (const float*)d_in[6];
    const float* Wl   = (const float*)d_in[7];
    const float* bl   = (const float*)d_in[8];
    const float* Wr   = (const float*)d_in[9];
    const float* br   = (const float*)d_in[10];
    const float* We   = (const float*)d_in[11];
    const float* att  = (const float*)d_in[12];
    const float* bias_gat = (const float*)d_in[13];
    const float* W1   = (const float*)d_in[14];
    const float* b1   = (const float*)d_in[15];
    const float* g2   = (const float*)d_in[16];
    const float* be2  = (const float*)d_in[17];
    const float* rm2  = (const float*)d_in[18];
    const float* rv2  = (const float*)d_in[19];
    const float* W2   = (const float*)d_in[20];
    const float* b2   = (const float*)d_in[21];

    float* ws   = (float*)d_ws;
    float* hbn  = ws + OFF_HBN;
    float* acc  = ws + OFF_ACC;
    float* wpk  = ws + OFF_WPK;

    k_prep<<<(N_NODES * 16 + 255) / 256, 256, 0, stream>>>(
        h, g1, be1, rm1, rv1, Wl, bl, Wr, br, We, att, hbn, acc, wpk);
    k_edge<<<(N_EDGES + 255) / 256, 256, 0, stream>>>(hbn, ei, ew, wpk, acc);
    k_mlp<<<512, 256, 0, stream>>>(acc, Wl, bl, bias_gat, W1, b1, g2, be2, rm2, rv2, W2, b2,
                                   (float*)d_out);
}

// Round 7
// 100.386 us; speedup vs baseline: 3.5343x; 3.5343x over previous
//
#include <hip/hip_runtime.h>

#define N_NODES 50000
#define N_EDGES 400000
#define F_INP 5
#define HD 256          // HEADS*DIM = 2*128
#define BN_EPS 1e-5f

typedef short v8s __attribute__((ext_vector_type(8)));
typedef float v4f __attribute__((ext_vector_type(4)));
typedef unsigned v4u __attribute__((ext_vector_type(4)));

// ---- workspace layout (float offsets) ----
#define OFF_HBN 0          // N*8  (padded rows: 5 used + 3 pad)
#define OFF_ACC 400000     // N*16 (den0,S0[5],den1,S1[5],cnt,pad3)
#define OFF_BPK 1200000    // 16 tiles * 64 lanes * 2 dwords = 2048

// float -> bf16 RNE
__device__ __forceinline__ unsigned short f2bf(float f) {
    unsigned u = __float_as_uint(f);
    return (unsigned short)((u + 0x7FFFu + ((u >> 16) & 1u)) >> 16);
}
__device__ __forceinline__ unsigned pk2(float a, float b) {
    return (unsigned)f2bf(a) | ((unsigned)f2bf(b) << 16);
}

// W_cat[k][c]: k 0..4 = Wl, 5..9 = Wr, 10 = We, 11 = bl+br
__device__ __forceinline__ float wcat(int k, int c, const float* Wl, const float* Wr,
                                      const float* We, const float* bl, const float* br) {
    if (k < 5)   return Wl[k * HD + c];
    if (k < 10)  return Wr[(k - 5) * HD + c];
    if (k == 10) return We[c];
    return bl[c] + br[c];
}

// prep: zero acc + BN1 -> hbn8 + pack B fragments (bf16, MFMA layout)
__global__ void k_prep(const float* __restrict__ h, const float* __restrict__ g1,
                       const float* __restrict__ be1, const float* __restrict__ rm1,
                       const float* __restrict__ rv1,
                       const float* __restrict__ Wl, const float* __restrict__ bl,
                       const float* __restrict__ Wr, const float* __restrict__ br,
                       const float* __restrict__ We, const float* __restrict__ att,
                       float* __restrict__ hbn8, float* __restrict__ acc,
                       unsigned* __restrict__ Bpk) {
    int i = blockIdx.x * blockDim.x + threadIdx.x;
    if (i < N_NODES * 16) acc[i] = 0.f;
    if (i < N_NODES * 8) {
        int f = i & 7, n = i >> 3;
        float v = 0.f;
        if (f < F_INP) {
            float x = h[n * F_INP + f];
            v = (x - rm1[f]) * rsqrtf(rv1[f] + BN_EPS) * g1[f] + be1[f];
        }
        hbn8[i] = v;
    }
    if (i < 1024) {  // B fragment pack: tile t, lane l
        int t = i >> 6, l = i & 63;
        int g = l >> 4, c = t * 16 + (l & 15);
        unsigned d0 = 0, d1 = 0;
        if (g < 3) {
            int kb = 4 * g;
            d0 = pk2(wcat(kb + 0, c, Wl, Wr, We, bl, br),
                     wcat(kb + 1, c, Wl, Wr, We, bl, br));
            d1 = pk2(wcat(kb + 2, c, Wl, Wr, We, bl, br),
                     wcat(kb + 3, c, Wl, Wr, We, bl, br));
        }
        Bpk[(t * 64 + l) * 2 + 0] = d0;
        Bpk[(t * 64 + l) * 2 + 1] = d1;
    }
}

// MFMA edge kernel, fully LDS-free: 16 edges per wave-iteration.
// U[16x256] = X[16x12] @ W_cat[12x256] via 16x16x32 bf16 MFMA (K zero-padded;
// the same k-slot permutation is applied to A and B packing, so A.B is exact).
// All cross-lane movement via __shfl (registers only) -> no memory races.
__launch_bounds__(256)
__global__ void k_edge(const float* __restrict__ hbn8, const int* __restrict__ ei,
                       const float* __restrict__ ew, const unsigned* __restrict__ Bpk,
                       const float* __restrict__ att, float* __restrict__ acc) {
    int lane = threadIdx.x & 63;
    int wv = threadIdx.x >> 6;
    int g = lane >> 4, e16 = lane & 15;

    // hoist B fragments + att (per-wave constants in VGPRs)
    v8s B[16];
    float AT[16];
#pragma unroll
    for (int t = 0; t < 16; ++t) {
        unsigned d0 = Bpk[(t * 64 + lane) * 2 + 0];
        unsigned d1 = Bpk[(t * 64 + lane) * 2 + 1];
        v4u u = {d0, d1, 0u, 0u};
        B[t] = __builtin_bit_cast(v8s, u);
        AT[t] = att[t * 16 + e16];
    }

    int wid = blockIdx.x * 4 + wv;
    int nw = gridDim.x * 4;
    const int NT = N_EDGES / 16;

    int q13 = lane / 13;               // scatter mapping (lanes 0..51)
    int j13 = lane - q13 * 13;
    bool sc_act = lane < 52;
    int kk = (j13 < 6) ? j13 - 1 : j13 - 7;
    int kc = min(max(kk, 0), 4);

    // loader regs (valid on lanes 0..15): x = [hs0..4, hd0..4, w]
    float x0 = 0, x1 = 0, x2 = 0, x3 = 0, x4 = 0,
          x5 = 0, x6 = 0, x7 = 0, x8 = 0, x9 = 0, x10 = 0;
    int dst_reg = 0;
    if (wid < NT && lane < 16) {
        int e = wid * 16 + lane;
        int src = ei[e];
        dst_reg = ei[N_EDGES + e];
        x10 = ew[e];
        float4 s4 = *(const float4*)&hbn8[src * 8];
        x0 = s4.x; x1 = s4.y; x2 = s4.z; x3 = s4.w;
        x4 = hbn8[src * 8 + 4];
        float4 d4 = *(const float4*)&hbn8[dst_reg * 8];
        x5 = d4.x; x6 = d4.y; x7 = d4.z; x8 = d4.w;
        x9 = hbn8[dst_reg * 8 + 4];
    }

    for (int tile = wid; tile < NT; tile += nw) {
        // broadcast phase: every lane gets row e16's values (register shfl)
        float b0 = __shfl(x0, e16), b1 = __shfl(x1, e16), b2 = __shfl(x2, e16),
              b3 = __shfl(x3, e16), b4 = __shfl(x4, e16), b5 = __shfl(x5, e16),
              b6 = __shfl(x6, e16), b7 = __shfl(x7, e16), b8 = __shfl(x8, e16),
              b9 = __shfl(x9, e16), b10 = __shfl(x10, e16);
        int dst_b = __shfl(dst_reg, e16);

        // A fragment pack: lane group g holds X[e16][4g..4g+3] (g==3 -> zeros)
        float a0 = (g == 0) ? b0 : (g == 1) ? b4 : b8;
        float a1 = (g == 0) ? b1 : (g == 1) ? b5 : b9;
        float a2 = (g == 0) ? b2 : (g == 1) ? b6 : b10;
        float a3 = (g == 0) ? b3 : (g == 1) ? b7 : 1.0f;
        unsigned ua0 = (g < 3) ? pk2(a0, a1) : 0u;
        unsigned ua1 = (g < 3) ? pk2(a2, a3) : 0u;
        v4u uav = {ua0, ua1, 0u, 0u};
        v8s A = __builtin_bit_cast(v8s, uav);

        // prefetch next tile's edge data into loader regs (hides under MFMA)
        int tn = tile + nw;
        if (tn < NT && lane < 16) {
            int e = tn * 16 + lane;
            int src = ei[e];
            dst_reg = ei[N_EDGES + e];
            x10 = ew[e];
            float4 s4 = *(const float4*)&hbn8[src * 8];
            x0 = s4.x; x1 = s4.y; x2 = s4.z; x3 = s4.w;
            x4 = hbn8[src * 8 + 4];
            float4 d4 = *(const float4*)&hbn8[dst_reg * 8];
            x5 = d4.x; x6 = d4.y; x7 = d4.z; x8 = d4.w;
            x9 = hbn8[dst_reg * 8 + 4];
        }

        // MFMA + epilogue: p_h = sum_c att_c * (u + (2/3)|u|)
        float p00 = 0.f, p01 = 0.f, p02 = 0.f, p03 = 0.f;
        float p10 = 0.f, p11 = 0.f, p12 = 0.f, p13v = 0.f;
        v4f zero = {0.f, 0.f, 0.f, 0.f};
#pragma unroll
        for (int t = 0; t < 8; ++t) {
            v4f c = __builtin_amdgcn_mfma_f32_16x16x32_bf16(A, B[t], zero, 0, 0, 0);
            p00 += AT[t] * fmaf(0.66666667f, fabsf(c[0]), c[0]);
            p01 += AT[t] * fmaf(0.66666667f, fabsf(c[1]), c[1]);
            p02 += AT[t] * fmaf(0.66666667f, fabsf(c[2]), c[2]);
            p03 += AT[t] * fmaf(0.66666667f, fabsf(c[3]), c[3]);
        }
#pragma unroll
        for (int t = 8; t < 16; ++t) {
            v4f c = __builtin_amdgcn_mfma_f32_16x16x32_bf16(A, B[t], zero, 0, 0, 0);
            p10 += AT[t] * fmaf(0.66666667f, fabsf(c[0]), c[0]);
            p11 += AT[t] * fmaf(0.66666667f, fabsf(c[1]), c[1]);
            p12 += AT[t] * fmaf(0.66666667f, fabsf(c[2]), c[2]);
            p13v += AT[t] * fmaf(0.66666667f, fabsf(c[3]), c[3]);
        }
        // reduce across the 16 channel-lanes of this group
#pragma unroll
        for (int m = 1; m <= 8; m <<= 1) {
            p00 += __shfl_xor(p00, m); p01 += __shfl_xor(p01, m);
            p02 += __shfl_xor(p02, m); p03 += __shfl_xor(p03, m);
            p10 += __shfl_xor(p10, m); p11 += __shfl_xor(p11, m);
            p12 += __shfl_xor(p12, m); p13v += __shfl_xor(p13v, m);
        }
        // exp (logit = 0.6 * p); lane-local select so lane l holds edge (l>>4)*4+(l&3)
        float e00 = __expf(0.6f * p00), e01 = __expf(0.6f * p01);
        float e02 = __expf(0.6f * p02), e03 = __expf(0.6f * p03);
        float e10 = __expf(0.6f * p10), e11 = __expf(0.6f * p11);
        float e12 = __expf(0.6f * p12), e13 = __expf(0.6f * p13v);
        float tA0 = (lane & 1) ? e01 : e00;
        float tA1 = (lane & 1) ? e03 : e02;
        float exA = (lane & 2) ? tA1 : tA0;   // ex head0 of edge (l>>4)*4+(l&3)
        float tB0 = (lane & 1) ? e11 : e10;
        float tB1 = (lane & 1) ? e13 : e12;
        float exB = (lane & 2) ? tB1 : tB0;   // ex head1

        // moment scatter: 4 iterations x (4 edges x 13 consecutive lanes)
        if (sc_act) {
#pragma unroll
            for (int it = 0; it < 4; ++it) {
                int es = it * 4 + q13;                 // edge-in-tile
                float h0 = __shfl(b0, es), h1 = __shfl(b1, es), h2 = __shfl(b2, es),
                      h3 = __shfl(b3, es), h4 = __shfl(b4, es);
                int de = __shfl(dst_b, es);
                float xh0 = __shfl(exA, it * 16 + q13);
                float xh1 = __shfl(exB, it * 16 + q13);
                float hsel = h0;
                hsel = (kc == 1) ? h1 : hsel;
                hsel = (kc == 2) ? h2 : hsel;
                hsel = (kc == 3) ? h3 : hsel;
                hsel = (kc == 4) ? h4 : hsel;
                float base = (j13 < 6) ? xh0 : xh1;
                float v = base * hsel;
                v = (j13 == 0) ? xh0 : v;
                v = (j13 == 6) ? xh1 : v;
                v = (j13 == 12) ? 1.0f : v;
                atomicAdd(&acc[de * 16 + j13], v);
            }
        }
    }
}

// fused: reconstruct aggregated feature from 12 moments -> fc1(LDS W1) -> BN2
//        -> lrelu -> fc2 -> out
__launch_bounds__(256, 1)
__global__ void k_mlp(const float* __restrict__ acc,
                      const float* __restrict__ Wl, const float* __restrict__ bl,
                      const float* __restrict__ bias_gat,
                      const float* __restrict__ W1, const float* __restrict__ b1,
                      const float* __restrict__ g2, const float* __restrict__ be2,
                      const float* __restrict__ rm2, const float* __restrict__ rv2,
                      const float* __restrict__ W2, const float* __restrict__ b2,
                      float* __restrict__ out) {
    __shared__ float wsh[128 * 128];
    __shared__ float xsh[8][128];
    __shared__ float wlsh[5 * 256 + 256 + 128];   // Wl | bl | bias_gat
    __shared__ float accsh[8][16];
    int t = threadIdx.x;
    for (int i = t; i < 128 * 128 / 4; i += 256)
        ((float4*)wsh)[i] = ((const float4*)W1)[i];
    for (int i = t; i < 5 * 256; i += 256) wlsh[i] = Wl[i];
    wlsh[1280 + t] = bl[t];
    if (t < 128) wlsh[1536 + t] = bias_gat[t];
    __syncthreads();
    const float* WL = wlsh;
    const float* BL = wlsh + 1280;
    const float* BG = wlsh + 1536;

    int nl = t >> 5;
    int jg = t & 31;
    int j4 = jg * 4;

    const int ngroups = (N_NODES + 7) / 8;
    for (int gr = blockIdx.x; gr < ngroups; gr += gridDim.x) {
        int n = gr * 8 + nl;
        if (t < 128) {
            int node = gr * 8 + (t >> 4);
            accsh[t >> 4][t & 15] = (node < N_NODES) ? acc[node * 16 + (t & 15)] : 0.f;
        }
        __syncthreads();
        bool valid = n < N_NODES;
        if (valid) {
            float den0 = accsh[nl][0], den1 = accsh[nl][6], cntv = accsh[nl][12];
            float r0 = 1.f / (den0 + 1e-16f), r1 = 1.f / (den1 + 1e-16f);
            float scale = 0.5f / fmaxf(cntv, 1.f);
            float c0 = den0 * r0 * scale, c1 = den1 * r1 * scale;
            float T0[F_INP], T1[F_INP];
#pragma unroll
            for (int f = 0; f < F_INP; ++f) {
                T0[f] = accsh[nl][1 + f] * r0 * scale;
                T1[f] = accsh[nl][7 + f] * r1 * scale;
            }
#pragma unroll
            for (int q = 0; q < 4; ++q) {
                int d = j4 + q;
                float xv = c0 * BL[d] + c1 * BL[128 + d];
#pragma unroll
                for (int f = 0; f < F_INP; ++f)
                    xv += T0[f] * WL[f * HD + d] + T1[f] * WL[f * HD + 128 + d];
                xsh[nl][d] = xv + BG[d];
            }
            float4 a4 = *(const float4*)&b1[j4];
#pragma unroll 8
            for (int k = 0; k < 128; ++k) {
                float xv = xsh[nl][k];
                float4 w = *(const float4*)&wsh[k * 128 + j4];
                a4.x += xv * w.x; a4.y += xv * w.y;
                a4.z += xv * w.z; a4.w += xv * w.w;
            }
            float4 rm = *(const float4*)&rm2[j4];
            float4 rv = *(const float4*)&rv2[j4];
            float4 gg = *(const float4*)&g2[j4];
            float4 bb = *(const float4*)&be2[j4];
            float a[4];
            a[0] = (a4.x - rm.x) * rsqrtf(rv.x + BN_EPS) * gg.x + bb.x;
            a[1] = (a4.y - rm.y) * rsqrtf(rv.y + BN_EPS) * gg.y + bb.y;
            a[2] = (a4.z - rm.z) * rsqrtf(rv.z + BN_EPS) * gg.z + bb.z;
            a[3] = (a4.w - rm.w) * rsqrtf(rv.w + BN_EPS) * gg.w + bb.w;
#pragma unroll
            for (int q = 0; q < 4; ++q) a[q] = fmaxf(a[q], 0.01f * a[q]);
            float pf[5] = {0.f, 0.f, 0.f, 0.f, 0.f};
#pragma unroll
            for (int q = 0; q < 4; ++q)
#pragma unroll
                for (int f = 0; f < 5; ++f) pf[f] += a[q] * W2[(j4 + q) * 5 + f];
#pragma unroll
            for (int m = 16; m; m >>= 1)
#pragma unroll
                for (int f = 0; f < 5; ++f) pf[f] += __shfl_xor(pf[f], m);
            if (jg == 0) {
#pragma unroll
                for (int f = 0; f < 5; ++f) out[n * 5 + f] = pf[f] + b2[f];
            }
        }
        __syncthreads();
    }
}

extern "C" void kernel_launch(void* const* d_in, const int* in_sizes, int n_in,
                              void* d_out, int out_size, void* d_ws, size_t ws_size,
                              hipStream_t stream) {
    const float* h    = (const float*)d_in[0];
    const int*   ei   = (const int*)d_in[1];
    const float* ew   = (const float*)d_in[2];
    const float* g1   = (const float*)d_in[3];
    const float* be1  = (const float*)d_in[4];
    const float* rm1  = (const float*)d_in[5];
    const float* rv1  = (const float*)d_in[6];
    const float* Wl   = (const float*)d_in[7];
    const float* bl   = (const float*)d_in[8];
    const float* Wr   = (const float*)d_in[9];
    const float* br   = (const float*)d_in[10];
    const float* We   = (const float*)d_in[11];
    const float* att  = (const float*)d_in[12];
    const float* bias_gat = (const float*)d_in[13];
    const float* W1   = (const float*)d_in[14];
    const float* b1   = (const float*)d_in[15];
    const float* g2   = (const float*)d_in[16];
    const float* be2  = (const float*)d_in[17];
    const float* rm2  = (const float*)d_in[18];
    const float* rv2  = (const float*)d_in[19];
    const float* W2   = (const float*)d_in[20];
    const float* b2   = (const float*)d_in[21];

    float* ws  = (float*)d_ws;
    float* hbn = ws + OFF_HBN;
    float* acc = ws + OFF_ACC;
    unsigned* Bpk = (unsigned*)(ws + OFF_BPK);

    k_prep<<<(N_NODES * 16 + 255) / 256, 256, 0, stream>>>(
        h, g1, be1, rm1, rv1, Wl, bl, Wr, br, We, att, hbn, acc, Bpk);
    k_edge<<<1024, 256, 0, stream>>>(hbn, ei, ew, Bpk, att, acc);
    k_mlp<<<512, 256, 0, stream>>>(acc, Wl, bl, bias_gat, W1, b1, g2, be2, rm2, rv2, W2, b2,
                                   (float*)d_out);
}